// Round 7
// baseline (36.159 us; speedup 1.0000x reference)
//
#include <hip/hip_runtime.h>
#include <hip/hip_fp16.h>
#include <math.h>

#define D_DET 512
#define N_ANG 180
#define S_IMG 512
#define NPIX  (S_IMG * S_IMG)
#define T_MAX 63                 // ramp tap truncation
#define TA    90                 // angles per LDS tile
#define WIN   64                 // detector window cells per angle

typedef _Float16 half2v __attribute__((ext_vector_type(2)));

__device__ __constant__ float kPI = 3.14159265358979323846f;

__device__ __forceinline__ half2v pack_weights(float a, float b) {
    return __builtin_bit_cast(half2v, __builtin_amdgcn_cvt_pkrtz(a, b));
}

// ---------------------------------------------------------------------------
// Stage 1: ramp filter, truncated symmetric convolution, fp16 packed output.
//   xf[d] = 0.5*r[d] + sum_{t odd,<=63} h(t)*(r[d-t]+r[d+t]), h(t)=-2/(pi t)^2
// Output word (a*512+d)*2+bc = packed fp16 (xf[d], xf[d+1]), xf[512]=0.
// ---------------------------------------------------------------------------
__global__ __launch_bounds__(512) void ramp_filter_kernel(
    const float* __restrict__ x, unsigned* __restrict__ xfh) {
    __shared__ float rp[640];            // [0,64)=0, [64,576)=row, [576,640)=0
    __shared__ float xf[D_DET + 1];

    const int a  = blockIdx.x >> 1;
    const int bc = blockIdx.x & 1;
    const int d  = threadIdx.x;

    if (d < 64)   rp[d] = 0.0f;
    if (d >= 448) rp[d + 128] = 0.0f;
    rp[64 + d] = x[(bc * D_DET + d) * N_ANG + a];
    if (d == 0) xf[D_DET] = 0.0f;
    __syncthreads();

    constexpr float PI_ = 3.14159265358979323846f;
    const float* rm = &rp[64 + d];
    float acc = 0.5f * rm[0];
    #pragma unroll
    for (int k = 0; k < (T_MAX + 1) / 2; ++k) {
        const int   t = 2 * k + 1;
        const float h = -2.0f / (PI_ * PI_ * (float)(t * t));   // literal
        acc = fmaf(rm[-t] + rm[t], h, acc);
    }
    xf[d] = acc;
    __syncthreads();

    const unsigned lo = __half_as_ushort(__float2half_rn(xf[d]));
    const unsigned hi = __half_as_ushort(__float2half_rn(xf[d + 1]));
    xfh[(a * D_DET + d) * 2 + bc] = (hi << 16) | lo;
}

// ---------------------------------------------------------------------------
// Stage 2: backprojection with LDS-staged detector windows.
// Block = 32(j) x 16(i) pixel tile, 256 threads, thread = 2 consecutive j.
// Per angle the tile's detector footprint (<= 35 cells) fits a 64-cell
// window; stage [TA=90][WIN=64] fp16-pair cells (46 KB) per half, gather
// with ds_read_b64, lerp via v_cvt_pkrtz + v_dot2_f32_f16.
// Grid: 512 blocks (16 j-tiles x 32 i-tiles) x 256 threads, 2 blocks/CU.
// ---------------------------------------------------------------------------
__global__ __launch_bounds__(256) void backproj_kernel(
    const uint2* __restrict__ xfh, float* __restrict__ out) {
    __shared__ float4 ang[N_ANG];        // (c*255.5, s*255.5, off_bits, dmin_bits)
    __shared__ uint2  win[TA * WIN];     // 46 KB window buffer

    const int tid = threadIdx.x;
    const int j0  = (blockIdx.x & 15) << 5;   // 16 j-tiles of 32
    const int i0  = (blockIdx.x >> 4) << 4;   // 32 i-tiles of 16

    // Prologue: per-angle trig + tile detector-window start.
    if (tid < N_ANG) {
        float th = (float)tid * (kPI / 180.0f);
        float s, c;
        sincosf(th, &s, &c);
        float c5 = c * 255.5f, s5 = s * 255.5f;
        float x0 = (float)j0 * (2.0f / 511.0f) - 1.0f;
        float x1 = (float)(j0 + 31) * (2.0f / 511.0f) - 1.0f;
        float y0 = (float)i0 * (2.0f / 511.0f) - 1.0f;
        float y1 = (float)(i0 + 15) * (2.0f / 511.0f) - 1.0f;
        float pmin = 255.5f + fminf(c5 * x0, c5 * x1) + fminf(-s5 * y0, -s5 * y1);
        int dmin = (int)floorf(pmin) - 1;
        dmin = dmin < 0 ? 0 : (dmin > (D_DET - WIN) ? (D_DET - WIN) : dmin);
        dmin &= ~1;                       // 16B-aligned staging source
        int al = (tid < TA) ? tid : tid - TA;
        ang[tid] = make_float4(c5, s5,
                               __int_as_float((al << 6) - dmin),
                               __int_as_float(dmin));
    }
    __syncthreads();

    const int il = tid >> 4;
    const int i  = i0 + il;
    const int j  = j0 + ((tid & 15) << 1);
    const float xA = (float)j * (2.0f / 511.0f) - 1.0f;
    const float xB = (float)(j + 1) * (2.0f / 511.0f) - 1.0f;
    const float yP = (float)i * (2.0f / 511.0f) - 1.0f;

    float a0A = 0.0f, a1A = 0.0f, a0B = 0.0f, a1B = 0.0f;
    const uint4* __restrict__ src4 = (const uint4*)xfh;
    uint4* win4 = (uint4*)win;

    for (int t = 0; t < 2; ++t) {
        // Stage TA angle windows: coalesced uint4 from L2 -> LDS (linear).
        for (int f = tid; f < TA * (WIN / 2); f += 256) {
            int a    = f >> 5;            // WIN/2 = 32 uint4 per angle
            int e    = f & 31;
            int ag   = t * TA + a;
            int dmin = __float_as_int(ang[ag].w);
            win4[f]  = src4[(ag << 8) + (dmin >> 1) + e];
        }
        __syncthreads();

        #pragma unroll 3
        for (int al = 0; al < TA; ++al) {
            float4 A   = ang[t * TA + al];
            float  by  = fmaf(yP, -A.y, 255.5f);
            int    off = __float_as_int(A.z);
            // pixel A
            {
                float pc = fminf(fmaxf(fmaf(xA, A.x, by), 0.0f), 511.0f);
                float fi = floorf(pc);
                float w  = pc - fi;
                half2v hw = pack_weights(1.0f - w, w);
                uint2  g  = win[off + (int)fi];
                a0A = __builtin_amdgcn_fdot2(hw, __builtin_bit_cast(half2v, g.x), a0A, false);
                a1A = __builtin_amdgcn_fdot2(hw, __builtin_bit_cast(half2v, g.y), a1A, false);
            }
            // pixel B
            {
                float pc = fminf(fmaxf(fmaf(xB, A.x, by), 0.0f), 511.0f);
                float fi = floorf(pc);
                float w  = pc - fi;
                half2v hw = pack_weights(1.0f - w, w);
                uint2  g  = win[off + (int)fi];
                a0B = __builtin_amdgcn_fdot2(hw, __builtin_bit_cast(half2v, g.x), a0B, false);
                a1B = __builtin_amdgcn_fdot2(hw, __builtin_bit_cast(half2v, g.y), a1B, false);
            }
        }
        __syncthreads();                  // before next tile overwrites win
    }

    const float scale = kPI / (2.0f * (float)N_ANG);
    const float mA = (xA * xA + yP * yP <= 1.0f) ? scale : 0.0f;
    const float mB = (xB * xB + yP * yP <= 1.0f) ? scale : 0.0f;
    const int p = i * S_IMG + j;
    *(float2*)(out + p)        = make_float2(a0A * mA, a0B * mB);
    *(float2*)(out + NPIX + p) = make_float2(a1A * mA, a1B * mB);
}

// ---------------------------------------------------------------------------
extern "C" void kernel_launch(void* const* d_in, const int* in_sizes, int n_in,
                              void* d_out, int out_size, void* d_ws, size_t ws_size,
                              hipStream_t stream) {
    const float* x   = (const float*)d_in[0];
    float*       out = (float*)d_out;
    unsigned*    xfh = (unsigned*)d_ws;  // 180*512*8 = 737,280 bytes

    ramp_filter_kernel<<<N_ANG * 2, 512, 0, stream>>>(x, xfh);
    backproj_kernel<<<512, 256, 0, stream>>>((const uint2*)xfh, out);
}

// Round 8
// 34.364 us; speedup vs baseline: 1.0522x; 1.0522x over previous
//
#include <hip/hip_runtime.h>
#include <hip/hip_fp16.h>
#include <math.h>

#define D_DET 512
#define N_ANG 180
#define S_IMG 512
#define NPIX  (S_IMG * S_IMG)
#define T_MAX 63                 // ramp tap truncation

typedef _Float16 half2v __attribute__((ext_vector_type(2)));

__device__ __constant__ float kPI = 3.14159265358979323846f;

__device__ __forceinline__ half2v pack_weights(float a, float b) {
    return __builtin_bit_cast(half2v, __builtin_amdgcn_cvt_pkrtz(a, b));
}

// ---------------------------------------------------------------------------
// Stage 1: ramp filter, truncated symmetric convolution, fp16 packed output.
//   xf[d] = 0.5*r[d] + sum_{t odd,<=63} h(t)*(r[d-t]+r[d+t]), h(t)=-2/(pi t)^2
// Output word (a*512+d)*2+bc = packed fp16 (xf[d], xf[d+1]), xf[512]=0.
// ---------------------------------------------------------------------------
__global__ __launch_bounds__(512) void ramp_filter_kernel(
    const float* __restrict__ x, unsigned* __restrict__ xfh) {
    __shared__ float rp[640];            // [0,64)=0, [64,576)=row, [576,640)=0
    __shared__ float xf[D_DET + 1];

    const int a  = blockIdx.x >> 1;
    const int bc = blockIdx.x & 1;
    const int d  = threadIdx.x;

    if (d < 64)   rp[d] = 0.0f;
    if (d >= 448) rp[d + 128] = 0.0f;
    rp[64 + d] = x[(bc * D_DET + d) * N_ANG + a];
    if (d == 0) xf[D_DET] = 0.0f;
    __syncthreads();

    constexpr float PI_ = 3.14159265358979323846f;
    const float* rm = &rp[64 + d];
    float acc = 0.5f * rm[0];
    #pragma unroll
    for (int k = 0; k < (T_MAX + 1) / 2; ++k) {
        const int   t = 2 * k + 1;
        const float h = -2.0f / (PI_ * PI_ * (float)(t * t));   // literal
        acc = fmaf(rm[-t] + rm[t], h, acc);
    }
    xf[d] = acc;
    __syncthreads();

    const unsigned lo = __half_as_ushort(__float2half_rn(xf[d]));
    const unsigned hi = __half_as_ushort(__float2half_rn(xf[d + 1]));
    xfh[(a * D_DET + d) * 2 + bc] = (hi << 16) | lo;
}

// ---------------------------------------------------------------------------
// Stage 2: backprojection, wave-compact 8x8 pixel tiles, pure L1 gather.
// Per angle a wave's 64 lanes span <= 7(|cos|+|sin|)+1 ~ 11 detector cells
// (~2-3 L1 lines) instead of 64 consecutive j (~9 lines) -> ~3-4x fewer
// line lookups in the TA/TD gather pipe (the measured bottleneck R4-R7).
// Thread = one pixel, both bc images: one 8B uint2 gather per angle.
// Block = 16x16 pixels (4 waves of 8x8). Grid 1024 x 256. Tiny LDS.
// ---------------------------------------------------------------------------
__global__ __launch_bounds__(256) void backproj_kernel(
    const uint2* __restrict__ xfh, float* __restrict__ out) {
    __shared__ float2 trig[N_ANG];       // (cos*255.5, sin*255.5)
    const int tid = threadIdx.x;
    if (tid < N_ANG) {
        float th = (float)tid * (kPI / 180.0f);
        float s, c;
        sincosf(th, &s, &c);
        trig[tid] = make_float2(c * 255.5f, s * 255.5f);
    }
    __syncthreads();

    const int bi   = blockIdx.x >> 5;    // 32 i-tiles of 16
    const int bj   = blockIdx.x & 31;    // 32 j-tiles of 16
    const int wave = tid >> 6;
    const int lane = tid & 63;
    const int i = (bi << 4) + ((wave >> 1) << 3) + (lane >> 3);
    const int j = (bj << 4) + ((wave & 1) << 3) + (lane & 7);

    const float xP = (float)j * (2.0f / 511.0f) - 1.0f;
    const float yP = (float)i * (2.0f / 511.0f) - 1.0f;
    const float m  = xP * xP + yP * yP;
    const int  p   = i * S_IMG + j;

    if (!__any(m <= 1.0f)) {             // whole 8x8 patch outside circle
        out[p]        = 0.0f;
        out[NPIX + p] = 0.0f;
        return;
    }

    float a0 = 0.0f, a1 = 0.0f;
    #pragma unroll 4
    for (int a = 0; a < N_ANG; ++a) {
        float2 t  = trig[a];
        float pc  = fminf(fmaxf(fmaf(xP, t.x, fmaf(yP, -t.y, 255.5f)), 0.0f), 511.0f);
        float fi  = floorf(pc);
        float w   = pc - fi;
        half2v hw = pack_weights(1.0f - w, w);
        uint2  g  = xfh[(a << 9) + (int)fi];
        a0 = __builtin_amdgcn_fdot2(hw, __builtin_bit_cast(half2v, g.x), a0, false);
        a1 = __builtin_amdgcn_fdot2(hw, __builtin_bit_cast(half2v, g.y), a1, false);
    }

    const float msk = (m <= 1.0f) ? (kPI / (2.0f * (float)N_ANG)) : 0.0f;
    out[p]        = a0 * msk;
    out[NPIX + p] = a1 * msk;
}

// ---------------------------------------------------------------------------
extern "C" void kernel_launch(void* const* d_in, const int* in_sizes, int n_in,
                              void* d_out, int out_size, void* d_ws, size_t ws_size,
                              hipStream_t stream) {
    const float* x   = (const float*)d_in[0];
    float*       out = (float*)d_out;
    unsigned*    xfh = (unsigned*)d_ws;  // 180*512*8 = 737,280 bytes

    ramp_filter_kernel<<<N_ANG * 2, 512, 0, stream>>>(x, xfh);
    backproj_kernel<<<1024, 256, 0, stream>>>((const uint2*)xfh, out);
}